// Round 9
// baseline (169.342 us; speedup 1.0000x reference)
//
#include <hip/hip_runtime.h>
#include <hip/hip_bf16.h>
#include <stdint.h>

#define NTOK 4096
#define DIN  2048
#define DOUT 2048
#define RANK 16
#define NLORA 32

typedef __attribute__((ext_vector_type(4))) float f32x4;
typedef __attribute__((ext_vector_type(8))) _Float16 f16x8;
typedef __attribute__((ext_vector_type(4))) _Float16 f16x4;

typedef const __attribute__((address_space(1))) void* gas_ptr;
typedef __attribute__((address_space(3))) void* las_ptr;

__device__ __forceinline__ f16x8 cvt8(const float* p) {
    f32x4 a = *(const f32x4*)(p);
    f32x4 b = *(const f32x4*)(p + 4);
    f16x8 h;
    h[0] = (_Float16)a.x; h[1] = (_Float16)a.y; h[2] = (_Float16)a.z; h[3] = (_Float16)a.w;
    h[4] = (_Float16)b.x; h[5] = (_Float16)b.y; h[6] = (_Float16)b.z; h[7] = (_Float16)b.w;
    return h;
}

// ---------------------------------------------------------------------------
// K1: single fused launch, 512 threads/block.
//   blocks [0,256):     LoRA (adapter a = b>>3, 32-token tile q = b&7).
//                       In-block 8-wave ballot scan of ids -> token list;
//                       reads x/lA/lB as f32 with inline cvt (no deps).
//   blocks [256,768):   W  f32->fp16 (16 elems/thread)
//   blocks [768,1792):  x  f32->fp16
// LoRA blocks first: 256 long poles start immediately, converts stream after.
// ---------------------------------------------------------------------------
__global__ __launch_bounds__(512)
void fused_prep_lora(const float* __restrict__ x, const int* __restrict__ ids,
                     const float* __restrict__ W, const float* __restrict__ lA,
                     const float* __restrict__ lB, const float* __restrict__ bias,
                     const float* __restrict__ scal,
                     _Float16* __restrict__ xh, _Float16* __restrict__ wh,
                     _Float16* __restrict__ Bresh) {
    const int bid = blockIdx.x;
    const int tid = threadIdx.x;
    if (bid >= 256) {
        const float* src; _Float16* dst; int lb;
        if (bid < 768) { src = W; dst = wh; lb = bid - 256; }
        else           { src = x; dst = xh; lb = bid - 768; }
        const size_t i = ((size_t)lb * 512 + tid) * 16;
        *(f16x8*)(dst + i)     = cvt8(src + i);
        *(f16x8*)(dst + i + 8) = cvt8(src + i + 8);
        return;
    }
    // ---------------- LoRA block: adapter a, token-tile q (32 tokens) -------
    const int a = bid >> 3, q = bid & 7;
    const int wv = tid >> 6;
    const int lane = tid & 63;
    const int fr = lane & 15, fq = lane >> 4;

    __shared__ int wvcnt[8];
    __shared__ int toks[32];
    __shared__ float red[8][2][256];
    __shared__ _Float16 ares_h[32 * RANK];

    if (tid < 32) toks[tid] = 0;                 // safe default
    // pass 1: per-wave match counts (wave wv scans tokens [wv*512, +512))
    int cw = 0;
#pragma unroll
    for (int r = 0; r < 8; r++)
        cw += __popcll(__ballot(ids[wv * 512 + r * 64 + lane] == a));
    if (lane == 0) wvcnt[wv] = cw;
    __syncthreads();
    int off = 0, cnt = 0;
#pragma unroll
    for (int w = 0; w < 8; w++) { if (w < wv) off += wvcnt[w]; cnt += wvcnt[w]; }
    // pass 2: scatter this tile's 32 token ids into LDS
    const int base = q * 32;
    int run = off;
#pragma unroll
    for (int r = 0; r < 8; r++) {
        const int t = wv * 512 + r * 64 + lane;
        const bool m = (ids[t] == a);
        const unsigned long long bal = __ballot(m);
        if (m) {
            const int pos = run + __popcll(bal & ((1ULL << lane) - 1));
            const int rel = pos - base;
            if (rel >= 0 && rel < 32) toks[rel] = t;
        }
        run += __popcll(bal);
    }
    __syncthreads();
    if (base >= cnt) return;

    // ---- stage 1: ares[32 tok][16 r] = scal * x @ lA^T (8-wave K-split) ----
    // (fragment roles identical to round-5/7 validated stage 1; lA f32+cvt,
    //  bf shared across both 16-token groups)
    const int t0 = toks[fr], t1 = toks[16 + fr];
    const float* xr0 = x + (size_t)t0 * DIN + wv * 256 + fq * 8;
    const float* xr1 = x + (size_t)t1 * DIN + wv * 256 + fq * 8;
    const float* ar = lA + (size_t)a * RANK * DIN + (size_t)fr * DIN + wv * 256 + fq * 8;
    f32x4 acc0 = (f32x4){0.f, 0.f, 0.f, 0.f};
    f32x4 acc1 = acc0;
#pragma unroll
    for (int st = 0; st < 8; st++) {
        const f16x8 bf = cvt8(ar + st * 32);
        acc0 = __builtin_amdgcn_mfma_f32_16x16x32_f16(cvt8(xr0 + st * 32), bf, acc0, 0, 0, 0);
        acc1 = __builtin_amdgcn_mfma_f32_16x16x32_f16(cvt8(xr1 + st * 32), bf, acc1, 0, 0, 0);
    }
#pragma unroll
    for (int j = 0; j < 4; j++) {
        red[wv][0][lane * 4 + j] = acc0[j];
        red[wv][1][lane * 4 + j] = acc1[j];
    }
    __syncthreads();
    if (wv < 2) {
        const int g = wv;
        const float s = scal[a];
#pragma unroll
        for (int j = 0; j < 4; j++) {
            float v = 0.f;
#pragma unroll
            for (int w = 0; w < 8; w++) v += red[w][g][lane * 4 + j];
            ares_h[(g * 16 + fq * 4 + j) * RANK + fr] = (_Float16)(v * s);
        }
    }
    __syncthreads();

    // ---- stage 2: Bresh = bias + ares @ lB^T (round-7 swapped operands,
    //      C[o][token] -> 8B vector stores), lB f32+cvt, bfrag shared over g --
    f16x8 aresf[2] = {{}, {}};
    if (fq < 2) {
        aresf[0] = *(const f16x8*)(ares_h + (size_t)fr * RANK + fq * 8);
        aresf[1] = *(const f16x8*)(ares_h + (size_t)(16 + fr) * RANK + fq * 8);
    }
    const bool val0 = (base + fr < cnt);
    const bool val1 = (base + 16 + fr < cnt);
    const float* Bb = lB + (size_t)a * DOUT * RANK;
    _Float16* orow0 = Bresh + (size_t)t0 * DOUT;
    _Float16* orow1 = Bresh + (size_t)t1 * DOUT;
#pragma unroll 4
    for (int oi = 0; oi < 16; oi++) {
        const int ot = wv * 16 + oi;
        f16x8 bfrag = {};
        if (fq < 2) bfrag = cvt8(Bb + (size_t)(ot * 16 + fr) * RANK + fq * 8);
        f32x4 c0 = (f32x4){0.f, 0.f, 0.f, 0.f};
        f32x4 c1 = c0;
        c0 = __builtin_amdgcn_mfma_f32_16x16x32_f16(bfrag, aresf[0], c0, 0, 0, 0);
        c1 = __builtin_amdgcn_mfma_f32_16x16x32_f16(bfrag, aresf[1], c1, 0, 0, 0);
        const f32x4 bv = *(const f32x4*)(bias + ot * 16 + fq * 4);
        if (val0) {
            f16x4 o4;
            o4[0] = (_Float16)(c0[0] + bv.x); o4[1] = (_Float16)(c0[1] + bv.y);
            o4[2] = (_Float16)(c0[2] + bv.z); o4[3] = (_Float16)(c0[3] + bv.w);
            *(f16x4*)(orow0 + ot * 16 + fq * 4) = o4;
        }
        if (val1) {
            f16x4 o4;
            o4[0] = (_Float16)(c1[0] + bv.x); o4[1] = (_Float16)(c1[1] + bv.y);
            o4[2] = (_Float16)(c1[2] + bv.z); o4[3] = (_Float16)(c1[3] + bv.w);
            *(f16x4*)(orow1 + ot * 16 + fq * 4) = o4;
        }
    }
}

// ---------------------------------------------------------------------------
// K2: main GEMM fp16 — EXACT round-5/7 kernel (42 us, MfmaUtil 32%,
// conflicts 0). 128x128, 4 waves, BK=64, 64 KB dbuf, counted vmcnt(8),
// 8-slot swizzle, XCD-chunked block swizzle.
// ---------------------------------------------------------------------------
#define GBK 64
#define NT (DIN / GBK)

__global__ __launch_bounds__(256, 2)
void gemm_kernel(const _Float16* __restrict__ Ah, const _Float16* __restrict__ Wh,
                 const _Float16* __restrict__ Bresh, float* __restrict__ out) {
    extern __shared__ _Float16 sm[];
    _Float16* As = sm;             // 2 x 8192 halfs
    _Float16* Bs = sm + 16384;     // 2 x 8192 halfs

    const int tid = threadIdx.x;
    const int wave = tid >> 6;
    const int lane = tid & 63;
    const int wr = wave >> 1, wc = wave & 1;

    const int p = blockIdx.x;
    const int L = (p & 7) * 64 + (p >> 3);
    const int bm = (L >> 4) * 128;
    const int bn = (L & 15) * 128;

    const int rsub = lane >> 3;
    const int cch = (lane & 7) ^ rsub;
    const _Float16* srcA[4];
    const _Float16* srcB[4];
#pragma unroll
    for (int i = 0; i < 4; i++) {
        const int row = (wave * 4 + i) * 8 + rsub;
        srcA[i] = Ah + (size_t)(bm + row) * DIN + cch * 8;
        srcB[i] = Wh + (size_t)(bn + row) * DIN + cch * 8;
    }

    const int fr = lane & 15;
    const int fq = lane >> 4;

    f32x4 acc[4][4];
#pragma unroll
    for (int i = 0; i < 4; i++)
#pragma unroll
        for (int j = 0; j < 4; j++) acc[i][j] = (f32x4){0.f, 0.f, 0.f, 0.f};

#define STAGE(buf, koff)                                                                  \
    do {                                                                                  \
        _Pragma("unroll")                                                                 \
        for (int i = 0; i < 4; i++) {                                                     \
            __builtin_amdgcn_global_load_lds((gas_ptr)(srcA[i] + (koff)),                 \
                (las_ptr)(As + (buf) * 8192 + (wave * 4 + i) * 512), 16, 0, 0);           \
            __builtin_amdgcn_global_load_lds((gas_ptr)(srcB[i] + (koff)),                 \
                (las_ptr)(Bs + (buf) * 8192 + (wave * 4 + i) * 512), 16, 0, 0);           \
        }                                                                                 \
    } while (0)

    STAGE(0, 0);

    for (int kt = 0; kt < NT; ++kt) {
        const int cur = kt & 1;
        if (kt < NT - 1) {
            STAGE(cur ^ 1, (kt + 1) * GBK);
            asm volatile("s_waitcnt vmcnt(8)" ::: "memory");
        } else {
            asm volatile("s_waitcnt vmcnt(0)" ::: "memory");
        }
        __builtin_amdgcn_s_barrier();
        __builtin_amdgcn_sched_barrier(0);

        const _Float16* Ab = As + cur * 8192;
        const _Float16* Bb = Bs + cur * 8192;
#pragma unroll
        for (int kk = 0; kk < 2; kk++) {
            f16x8 av[4], bv[4];
#pragma unroll
            for (int mi = 0; mi < 4; mi++) {
                const int row = wr * 64 + mi * 16 + fr;
                const int slot = (kk * 4 + fq) ^ (row & 7);
                av[mi] = *(const f16x8*)(Ab + row * 64 + slot * 8);
            }
#pragma unroll
            for (int ni = 0; ni < 4; ni++) {
                const int row = wc * 64 + ni * 16 + fr;
                const int slot = (kk * 4 + fq) ^ (row & 7);
                bv[ni] = *(const f16x8*)(Bb + row * 64 + slot * 8);
            }
            __builtin_amdgcn_s_setprio(1);
#pragma unroll
            for (int mi = 0; mi < 4; mi++)
#pragma unroll
                for (int ni = 0; ni < 4; ni++)
                    acc[mi][ni] = __builtin_amdgcn_mfma_f32_16x16x32_f16(av[mi], bv[ni], acc[mi][ni], 0, 0, 0);
            __builtin_amdgcn_s_setprio(0);
        }
        __builtin_amdgcn_s_barrier();
    }

#pragma unroll
    for (int mi = 0; mi < 4; mi++) {
#pragma unroll
        for (int j = 0; j < 4; j++) {
            const int n = bm + wr * 64 + mi * 16 + fq * 4 + j;
#pragma unroll
            for (int ni = 0; ni < 4; ni++) {
                const int o = bn + wc * 64 + ni * 16 + fr;
                out[(size_t)n * DOUT + o] = acc[mi][ni][j] + (float)Bresh[(size_t)n * DOUT + o];
            }
        }
    }
}

extern "C" void kernel_launch(void* const* d_in, const int* in_sizes, int n_in,
                              void* d_out, int out_size, void* d_ws, size_t ws_size,
                              hipStream_t stream) {
    const float* x    = (const float*)d_in[0];
    const int*   ids  = (const int*)d_in[1];
    const float* W    = (const float*)d_in[2];
    const float* bias = (const float*)d_in[3];
    const float* lA   = (const float*)d_in[4];
    const float* lB   = (const float*)d_in[5];
    const float* scal = (const float*)d_in[6];
    float* out = (float*)d_out;

    _Float16* xh    = (_Float16*)d_ws;                    // 16.8 MB
    _Float16* wh    = xh + (size_t)NTOK * DIN;            //  8.4 MB
    _Float16* Bresh = wh + (size_t)DOUT * DIN;            // 16.8 MB

    fused_prep_lora<<<dim3(1792), 512, 0, stream>>>(
        x, ids, W, lA, lB, bias, scal, xh, wh, Bresh);
    gemm_kernel<<<dim3(512), 256, 64 * 1024, stream>>>(
        xh, wh, Bresh, out);
}